// Round 1
// baseline (756.901 us; speedup 1.0000x reference)
//
#include <hip/hip_runtime.h>
#include <math.h>

#define NN 100000
#define NE 1250000
#define DIN 64
#define DHID 128
#define DO2 64   // concat(mu|lv)
#define DOUT 32

// ---------- small helpers ----------
__global__ void zero_two(int* a, int* b, int n) {
    int i = blockIdx.x * blockDim.x + threadIdx.x;
    if (i < n) { a[i] = 0; b[i] = 0; }
}

__global__ void count_dst(const int* __restrict__ dst, int* __restrict__ counts, int n) {
    int i = blockIdx.x * blockDim.x + threadIdx.x;
    if (i < n) atomicAdd(&counts[dst[i]], 1);
}

__global__ void compute_dis(const int* __restrict__ counts, float* __restrict__ dis, int n) {
    int i = blockIdx.x * blockDim.x + threadIdx.x;
    if (i < n) dis[i] = rsqrtf((float)counts[i] + 1.0f);  // +1 self-loop; always > 0
}

// single-block chunked Hillis-Steele exclusive scan (100k elems)
__global__ void scan_kernel(const int* __restrict__ counts, int* __restrict__ offsets, int n) {
    __shared__ int buf[1024];
    __shared__ int carry_s;
    int tid = threadIdx.x;
    if (tid == 0) carry_s = 0;
    __syncthreads();
    for (int base = 0; base < n; base += 1024) {
        int i = base + tid;
        int v = (i < n) ? counts[i] : 0;
        buf[tid] = v;
        __syncthreads();
        for (int off = 1; off < 1024; off <<= 1) {
            int t = (tid >= off) ? buf[tid - off] : 0;
            __syncthreads();
            buf[tid] += t;
            __syncthreads();
        }
        int incl = buf[tid];
        if (i < n) offsets[i] = carry_s + incl - v;   // exclusive
        __syncthreads();
        if (tid == 1023) carry_s += incl;
        __syncthreads();
    }
    if (tid == 0) offsets[n] = carry_s;
}

__global__ void scatter_edges(const int* __restrict__ src, const int* __restrict__ dst,
                              const int* __restrict__ offsets, int* __restrict__ cursor,
                              int* __restrict__ esrc, int n) {
    int i = blockIdx.x * blockDim.x + threadIdx.x;
    if (i < n) {
        int d = dst[i];
        int pos = offsets[d] + atomicAdd(&cursor[d], 1);
        esrc[pos] = src[i];
    }
}

__global__ void build_wcat(const float* __restrict__ Wmu, const float* __restrict__ Wlv,
                           float* __restrict__ Wcat) {
    int i = blockIdx.x * blockDim.x + threadIdx.x;  // 128*64
    if (i < DHID * DO2) {
        int k = i >> 6, j = i & 63;
        Wcat[i] = (j < DOUT) ? Wmu[k * DOUT + j] : Wlv[k * DOUT + (j - DOUT)];
    }
}

// ---------- GEMM1: x[N,64] @ W1[64,128] -> hw1[N,128] ----------
__global__ __launch_bounds__(256) void gemm1(const float* __restrict__ x,
                                             const float* __restrict__ W,
                                             float* __restrict__ out) {
    __shared__ float xs[32][65];
    __shared__ float Ws[64][128];
    int tid = threadIdx.x;
    int row0 = blockIdx.x * 32;

    for (int t = tid; t < (64 * 128) / 4; t += 256)
        ((float4*)Ws)[t] = ((const float4*)W)[t];
    for (int t = tid; t < (32 * 64) / 4; t += 256) {
        int r = t >> 4, c4 = t & 15;
        int row = row0 + r;
        float4 v = make_float4(0.f, 0.f, 0.f, 0.f);
        if (row < NN) v = ((const float4*)(x + (size_t)row * DIN))[c4];
        xs[r][c4 * 4 + 0] = v.x; xs[r][c4 * 4 + 1] = v.y;
        xs[r][c4 * 4 + 2] = v.z; xs[r][c4 * 4 + 3] = v.w;
    }
    __syncthreads();

    int r = tid >> 3;
    int c0 = (tid & 7) * 16;
    float acc[16];
#pragma unroll
    for (int j = 0; j < 16; j++) acc[j] = 0.f;
#pragma unroll
    for (int k = 0; k < 64; k++) {
        float a = xs[r][k];
#pragma unroll
        for (int j = 0; j < 16; j++) acc[j] += a * Ws[k][c0 + j];
    }
    int row = row0 + r;
    if (row < NN) {
        float4* o = (float4*)(out + (size_t)row * DHID + c0);
        o[0] = make_float4(acc[0], acc[1], acc[2], acc[3]);
        o[1] = make_float4(acc[4], acc[5], acc[6], acc[7]);
        o[2] = make_float4(acc[8], acc[9], acc[10], acc[11]);
        o[3] = make_float4(acc[12], acc[13], acc[14], acc[15]);
    }
}

// ---------- GEMM2: h[N,128] @ Wcat[128,64] -> hw2[N,64] ----------
__global__ __launch_bounds__(256) void gemm2(const float* __restrict__ h,
                                             const float* __restrict__ W,
                                             float* __restrict__ out) {
    __shared__ float hs[32][129];
    __shared__ float Ws[128][64];
    int tid = threadIdx.x;
    int row0 = blockIdx.x * 32;

    for (int t = tid; t < (128 * 64) / 4; t += 256)
        ((float4*)Ws)[t] = ((const float4*)W)[t];
    for (int t = tid; t < (32 * 128) / 4; t += 256) {
        int r = t >> 5, c4 = t & 31;
        int row = row0 + r;
        float4 v = make_float4(0.f, 0.f, 0.f, 0.f);
        if (row < NN) v = ((const float4*)(h + (size_t)row * DHID))[c4];
        hs[r][c4 * 4 + 0] = v.x; hs[r][c4 * 4 + 1] = v.y;
        hs[r][c4 * 4 + 2] = v.z; hs[r][c4 * 4 + 3] = v.w;
    }
    __syncthreads();

    int r = tid >> 3;
    int c0 = (tid & 7) * 8;
    float acc[8];
#pragma unroll
    for (int j = 0; j < 8; j++) acc[j] = 0.f;
#pragma unroll
    for (int k = 0; k < 128; k++) {
        float a = hs[r][k];
#pragma unroll
        for (int j = 0; j < 8; j++) acc[j] += a * Ws[k][c0 + j];
    }
    int row = row0 + r;
    if (row < NN) {
        float4* o = (float4*)(out + (size_t)row * DO2 + c0);
        o[0] = make_float4(acc[0], acc[1], acc[2], acc[3]);
        o[1] = make_float4(acc[4], acc[5], acc[6], acc[7]);
    }
}

__device__ __forceinline__ float selu_f(float v) {
    const float scale = 1.0507009873554805f;
    const float alpha = 1.6732632423543772f;
    return scale * (v > 0.f ? v : alpha * (expf(v) - 1.f));
}

// ---------- aggregate layer 1: one wave per node, 2 feats/lane, +bias +selu ----------
__global__ __launch_bounds__(256) void aggregate1(const float* __restrict__ hw,
                                                  const int* __restrict__ offsets,
                                                  const int* __restrict__ esrc,
                                                  const float* __restrict__ dis,
                                                  const float* __restrict__ b,
                                                  float* __restrict__ h) {
    int wave = threadIdx.x >> 6;
    int lane = threadIdx.x & 63;
    int v = blockIdx.x * 4 + wave;
    if (v >= NN) return;
    int beg = offsets[v], end = offsets[v + 1];
    float acc0 = 0.f, acc1 = 0.f;
    for (int i = beg; i < end; i++) {
        int s = esrc[i];
        float c = dis[s];
        const float* row = hw + (size_t)s * DHID;
        acc0 += c * row[lane];
        acc1 += c * row[lane + 64];
    }
    float dv = dis[v];
    const float* rowv = hw + (size_t)v * DHID;
    acc0 += dv * rowv[lane];
    acc1 += dv * rowv[lane + 64];
    float o0 = selu_f(dv * acc0 + b[lane]);
    float o1 = selu_f(dv * acc1 + b[lane + 64]);
    h[(size_t)v * DHID + lane] = o0;
    h[(size_t)v * DHID + lane + 64] = o1;
}

// ---------- aggregate layer 2: one wave per node, 1 feat/lane, split mu/logvar ----------
__global__ __launch_bounds__(256) void aggregate2(const float* __restrict__ hw2,
                                                  const int* __restrict__ offsets,
                                                  const int* __restrict__ esrc,
                                                  const float* __restrict__ dis,
                                                  const float* __restrict__ bmu,
                                                  const float* __restrict__ blv,
                                                  float* __restrict__ out) {
    int wave = threadIdx.x >> 6;
    int lane = threadIdx.x & 63;
    int v = blockIdx.x * 4 + wave;
    if (v >= NN) return;
    int beg = offsets[v], end = offsets[v + 1];
    float acc = 0.f;
    for (int i = beg; i < end; i++) {
        int s = esrc[i];
        acc += dis[s] * hw2[(size_t)s * DO2 + lane];
    }
    float dv = dis[v];
    acc += dv * hw2[(size_t)v * DO2 + lane];
    float bias = (lane < DOUT) ? bmu[lane] : blv[lane - DOUT];
    float o = dv * acc + bias;
    if (lane < DOUT)
        out[(size_t)v * DOUT + lane] = o;
    else
        out[(size_t)NN * DOUT + (size_t)v * DOUT + (lane - DOUT)] = o;
}

extern "C" void kernel_launch(void* const* d_in, const int* in_sizes, int n_in,
                              void* d_out, int out_size, void* d_ws, size_t ws_size,
                              hipStream_t stream) {
    const float* x   = (const float*)d_in[0];
    const int*   ei  = (const int*)d_in[1];
    const int*   e_src = ei;            // edge_index[0]
    const int*   e_dst = ei + NE;       // edge_index[1]
    const float* W1  = (const float*)d_in[2];
    const float* b1  = (const float*)d_in[3];
    const float* Wmu = (const float*)d_in[4];
    const float* bmu = (const float*)d_in[5];
    const float* Wlv = (const float*)d_in[6];
    const float* blv = (const float*)d_in[7];
    float* out = (float*)d_out;

    char* ws = (char*)d_ws;
    size_t off = 0;
    auto alloc = [&](size_t bytes) -> void* {
        void* p = ws + off;
        off += (bytes + 255) & ~(size_t)255;
        return p;
    };
    int*   counts  = (int*)alloc((size_t)NN * 4);
    int*   cursor  = (int*)alloc((size_t)NN * 4);
    int*   offsets = (int*)alloc((size_t)(NN + 1) * 4);
    int*   esrc    = (int*)alloc((size_t)NE * 4);
    float* dis     = (float*)alloc((size_t)NN * 4);
    float* Wcat    = (float*)alloc((size_t)DHID * DO2 * 4);
    float* hw1     = (float*)alloc((size_t)NN * DHID * 4);
    float* h       = (float*)alloc((size_t)NN * DHID * 4);
    float* hw2     = hw1;  // hw1 dead after aggregate1

    zero_two<<<(NN + 255) / 256, 256, 0, stream>>>(counts, cursor, NN);
    count_dst<<<(NE + 255) / 256, 256, 0, stream>>>(e_dst, counts, NE);
    compute_dis<<<(NN + 255) / 256, 256, 0, stream>>>(counts, dis, NN);
    scan_kernel<<<1, 1024, 0, stream>>>(counts, offsets, NN);
    scatter_edges<<<(NE + 255) / 256, 256, 0, stream>>>(e_src, e_dst, offsets, cursor, esrc, NE);
    build_wcat<<<(DHID * DO2 + 255) / 256, 256, 0, stream>>>(Wmu, Wlv, Wcat);

    gemm1<<<(NN + 31) / 32, 256, 0, stream>>>(x, W1, hw1);
    aggregate1<<<(NN + 3) / 4, 256, 0, stream>>>(hw1, offsets, esrc, dis, b1, h);
    gemm2<<<(NN + 31) / 32, 256, 0, stream>>>(h, Wcat, hw2);
    aggregate2<<<(NN + 3) / 4, 256, 0, stream>>>(hw2, offsets, esrc, dis, bmu, blv, out);
}

// Round 2
// 576.612 us; speedup vs baseline: 1.3127x; 1.3127x over previous
//
#include <hip/hip_runtime.h>
#include <math.h>

#define NN 100000
#define NE 1250000
#define DIN 64
#define DHID 128
#define DO2 64   // concat(mu|lv)
#define DOUT 32

#define SCAN_CHUNK 1024
#define SCAN_NB ((NN + SCAN_CHUNK - 1) / SCAN_CHUNK)   // 98

// ---------- small helpers ----------
__global__ void zero_two(int* a, int* b, int n) {
    int i = blockIdx.x * blockDim.x + threadIdx.x;
    if (i < n) { a[i] = 0; b[i] = 0; }
}

__global__ void count_dst(const int* __restrict__ dst, int* __restrict__ counts, int n) {
    int i = blockIdx.x * blockDim.x + threadIdx.x;
    if (i < n) atomicAdd(&counts[dst[i]], 1);
}

__global__ void compute_dis(const int* __restrict__ counts, float* __restrict__ dis, int n) {
    int i = blockIdx.x * blockDim.x + threadIdx.x;
    if (i < n) dis[i] = rsqrtf((float)counts[i] + 1.0f);  // +1 self-loop; always > 0
}

// ---------- hierarchical exclusive scan over counts[NN] ----------
__global__ __launch_bounds__(1024) void scan_phase1(const int* __restrict__ counts,
                                                    int* __restrict__ offsets,
                                                    int* __restrict__ blocksums, int n) {
    __shared__ int buf[SCAN_CHUNK];
    int tid = threadIdx.x;
    int i = blockIdx.x * SCAN_CHUNK + tid;
    int v = (i < n) ? counts[i] : 0;
    buf[tid] = v;
    __syncthreads();
    for (int off = 1; off < SCAN_CHUNK; off <<= 1) {
        int t = (tid >= off) ? buf[tid - off] : 0;
        __syncthreads();
        buf[tid] += t;
        __syncthreads();
    }
    if (i < n) offsets[i] = buf[tid] - v;            // block-local exclusive
    if (tid == SCAN_CHUNK - 1) blocksums[blockIdx.x] = buf[tid];
}

__global__ __launch_bounds__(128) void scan_phase2(int* __restrict__ blocksums, int nb) {
    __shared__ int buf[128];
    int tid = threadIdx.x;
    int v = (tid < nb) ? blocksums[tid] : 0;
    buf[tid] = v;
    __syncthreads();
    for (int off = 1; off < 128; off <<= 1) {
        int t = (tid >= off) ? buf[tid - off] : 0;
        __syncthreads();
        buf[tid] += t;
        __syncthreads();
    }
    if (tid < nb) blocksums[tid] = buf[tid] - v;     // exclusive block bases
}

__global__ __launch_bounds__(1024) void scan_phase3(int* __restrict__ offsets,
                                                    const int* __restrict__ blocksums, int n) {
    int i = blockIdx.x * SCAN_CHUNK + threadIdx.x;
    if (i < n) offsets[i] += blocksums[blockIdx.x];
    if (blockIdx.x == 0 && threadIdx.x == 0) offsets[n] = NE;  // total = E exactly
}

__global__ void scatter_edges(const int* __restrict__ src, const int* __restrict__ dst,
                              const int* __restrict__ offsets, int* __restrict__ cursor,
                              int* __restrict__ esrc, int n) {
    int i = blockIdx.x * blockDim.x + threadIdx.x;
    if (i < n) {
        int d = dst[i];
        int pos = offsets[d] + atomicAdd(&cursor[d], 1);
        esrc[pos] = src[i];
    }
}

__global__ void build_wcat(const float* __restrict__ Wmu, const float* __restrict__ Wlv,
                           float* __restrict__ Wcat) {
    int i = blockIdx.x * blockDim.x + threadIdx.x;  // 128*64
    if (i < DHID * DO2) {
        int k = i >> 6, j = i & 63;
        Wcat[i] = (j < DOUT) ? Wmu[k * DOUT + j] : Wlv[k * DOUT + (j - DOUT)];
    }
}

// ---------- GEMM1: x[N,64] @ W1[64,128] -> hw1[N,128] ----------
__global__ __launch_bounds__(256) void gemm1(const float* __restrict__ x,
                                             const float* __restrict__ W,
                                             float* __restrict__ out) {
    __shared__ float xs[32][65];
    __shared__ float Ws[64][128];
    int tid = threadIdx.x;
    int row0 = blockIdx.x * 32;

    for (int t = tid; t < (64 * 128) / 4; t += 256)
        ((float4*)Ws)[t] = ((const float4*)W)[t];
    for (int t = tid; t < (32 * 64) / 4; t += 256) {
        int r = t >> 4, c4 = t & 15;
        int row = row0 + r;
        float4 v = make_float4(0.f, 0.f, 0.f, 0.f);
        if (row < NN) v = ((const float4*)(x + (size_t)row * DIN))[c4];
        xs[r][c4 * 4 + 0] = v.x; xs[r][c4 * 4 + 1] = v.y;
        xs[r][c4 * 4 + 2] = v.z; xs[r][c4 * 4 + 3] = v.w;
    }
    __syncthreads();

    int r = tid >> 3;
    int c0 = (tid & 7) * 16;
    float acc[16];
#pragma unroll
    for (int j = 0; j < 16; j++) acc[j] = 0.f;
#pragma unroll
    for (int k = 0; k < 64; k++) {
        float a = xs[r][k];
#pragma unroll
        for (int j = 0; j < 16; j++) acc[j] += a * Ws[k][c0 + j];
    }
    int row = row0 + r;
    if (row < NN) {
        float4* o = (float4*)(out + (size_t)row * DHID + c0);
        o[0] = make_float4(acc[0], acc[1], acc[2], acc[3]);
        o[1] = make_float4(acc[4], acc[5], acc[6], acc[7]);
        o[2] = make_float4(acc[8], acc[9], acc[10], acc[11]);
        o[3] = make_float4(acc[12], acc[13], acc[14], acc[15]);
    }
}

// ---------- GEMM2: h[N,128] @ Wcat[128,64] -> hw2[N,64] ----------
__global__ __launch_bounds__(256) void gemm2(const float* __restrict__ h,
                                             const float* __restrict__ W,
                                             float* __restrict__ out) {
    __shared__ float hs[32][129];
    __shared__ float Ws[128][64];
    int tid = threadIdx.x;
    int row0 = blockIdx.x * 32;

    for (int t = tid; t < (128 * 64) / 4; t += 256)
        ((float4*)Ws)[t] = ((const float4*)W)[t];
    for (int t = tid; t < (32 * 128) / 4; t += 256) {
        int r = t >> 5, c4 = t & 31;
        int row = row0 + r;
        float4 v = make_float4(0.f, 0.f, 0.f, 0.f);
        if (row < NN) v = ((const float4*)(h + (size_t)row * DHID))[c4];
        hs[r][c4 * 4 + 0] = v.x; hs[r][c4 * 4 + 1] = v.y;
        hs[r][c4 * 4 + 2] = v.z; hs[r][c4 * 4 + 3] = v.w;
    }
    __syncthreads();

    int r = tid >> 3;
    int c0 = (tid & 7) * 8;
    float acc[8];
#pragma unroll
    for (int j = 0; j < 8; j++) acc[j] = 0.f;
#pragma unroll
    for (int k = 0; k < 128; k++) {
        float a = hs[r][k];
#pragma unroll
        for (int j = 0; j < 8; j++) acc[j] += a * Ws[k][c0 + j];
    }
    int row = row0 + r;
    if (row < NN) {
        float4* o = (float4*)(out + (size_t)row * DO2 + c0);
        o[0] = make_float4(acc[0], acc[1], acc[2], acc[3]);
        o[1] = make_float4(acc[4], acc[5], acc[6], acc[7]);
    }
}

__device__ __forceinline__ float selu_f(float v) {
    const float scale = 1.0507009873554805f;
    const float alpha = 1.6732632423543772f;
    return scale * (v > 0.f ? v : alpha * (expf(v) - 1.f));
}

// ---------- aggregate layer 1: one wave per node, 2 feats/lane, +bias +selu ----------
__global__ __launch_bounds__(256) void aggregate1(const float* __restrict__ hw,
                                                  const int* __restrict__ offsets,
                                                  const int* __restrict__ esrc,
                                                  const float* __restrict__ dis,
                                                  const float* __restrict__ b,
                                                  float* __restrict__ h) {
    int wave = threadIdx.x >> 6;
    int lane = threadIdx.x & 63;
    int v = blockIdx.x * 4 + wave;
    if (v >= NN) return;
    int beg = offsets[v], end = offsets[v + 1];
    float acc0 = 0.f, acc1 = 0.f;
    for (int i = beg; i < end; i++) {
        int s = esrc[i];
        float c = dis[s];
        const float* row = hw + (size_t)s * DHID;
        acc0 += c * row[lane];
        acc1 += c * row[lane + 64];
    }
    float dv = dis[v];
    const float* rowv = hw + (size_t)v * DHID;
    acc0 += dv * rowv[lane];
    acc1 += dv * rowv[lane + 64];
    float o0 = selu_f(dv * acc0 + b[lane]);
    float o1 = selu_f(dv * acc1 + b[lane + 64]);
    h[(size_t)v * DHID + lane] = o0;
    h[(size_t)v * DHID + lane + 64] = o1;
}

// ---------- aggregate layer 2: one wave per node, 1 feat/lane, split mu/logvar ----------
__global__ __launch_bounds__(256) void aggregate2(const float* __restrict__ hw2,
                                                  const int* __restrict__ offsets,
                                                  const int* __restrict__ esrc,
                                                  const float* __restrict__ dis,
                                                  const float* __restrict__ bmu,
                                                  const float* __restrict__ blv,
                                                  float* __restrict__ out) {
    int wave = threadIdx.x >> 6;
    int lane = threadIdx.x & 63;
    int v = blockIdx.x * 4 + wave;
    if (v >= NN) return;
    int beg = offsets[v], end = offsets[v + 1];
    float acc = 0.f;
    for (int i = beg; i < end; i++) {
        int s = esrc[i];
        acc += dis[s] * hw2[(size_t)s * DO2 + lane];
    }
    float dv = dis[v];
    acc += dv * hw2[(size_t)v * DO2 + lane];
    float bias = (lane < DOUT) ? bmu[lane] : blv[lane - DOUT];
    float o = dv * acc + bias;
    if (lane < DOUT)
        out[(size_t)v * DOUT + lane] = o;
    else
        out[(size_t)NN * DOUT + (size_t)v * DOUT + (lane - DOUT)] = o;
}

extern "C" void kernel_launch(void* const* d_in, const int* in_sizes, int n_in,
                              void* d_out, int out_size, void* d_ws, size_t ws_size,
                              hipStream_t stream) {
    const float* x   = (const float*)d_in[0];
    const int*   ei  = (const int*)d_in[1];
    const int*   e_src = ei;            // edge_index[0]
    const int*   e_dst = ei + NE;       // edge_index[1]
    const float* W1  = (const float*)d_in[2];
    const float* b1  = (const float*)d_in[3];
    const float* Wmu = (const float*)d_in[4];
    const float* bmu = (const float*)d_in[5];
    const float* Wlv = (const float*)d_in[6];
    const float* blv = (const float*)d_in[7];
    float* out = (float*)d_out;

    char* ws = (char*)d_ws;
    size_t off = 0;
    auto alloc = [&](size_t bytes) -> void* {
        void* p = ws + off;
        off += (bytes + 255) & ~(size_t)255;
        return p;
    };
    int*   counts    = (int*)alloc((size_t)NN * 4);
    int*   cursor    = (int*)alloc((size_t)NN * 4);
    int*   offsets   = (int*)alloc((size_t)(NN + 1) * 4);
    int*   esrc      = (int*)alloc((size_t)NE * 4);
    int*   blocksums = (int*)alloc((size_t)SCAN_NB * 4);
    float* dis       = (float*)alloc((size_t)NN * 4);
    float* Wcat      = (float*)alloc((size_t)DHID * DO2 * 4);
    float* hw1       = (float*)alloc((size_t)NN * DHID * 4);
    float* h         = (float*)alloc((size_t)NN * DHID * 4);
    float* hw2       = hw1;  // hw1 dead after aggregate1

    zero_two<<<(NN + 255) / 256, 256, 0, stream>>>(counts, cursor, NN);
    count_dst<<<(NE + 255) / 256, 256, 0, stream>>>(e_dst, counts, NE);
    compute_dis<<<(NN + 255) / 256, 256, 0, stream>>>(counts, dis, NN);
    scan_phase1<<<SCAN_NB, 1024, 0, stream>>>(counts, offsets, blocksums, NN);
    scan_phase2<<<1, 128, 0, stream>>>(blocksums, SCAN_NB);
    scan_phase3<<<SCAN_NB, 1024, 0, stream>>>(offsets, blocksums, NN);
    scatter_edges<<<(NE + 255) / 256, 256, 0, stream>>>(e_src, e_dst, offsets, cursor, esrc, NE);
    build_wcat<<<(DHID * DO2 + 255) / 256, 256, 0, stream>>>(Wmu, Wlv, Wcat);

    gemm1<<<(NN + 31) / 32, 256, 0, stream>>>(x, W1, hw1);
    aggregate1<<<(NN + 3) / 4, 256, 0, stream>>>(hw1, offsets, esrc, dis, b1, h);
    gemm2<<<(NN + 31) / 32, 256, 0, stream>>>(h, Wcat, hw2);
    aggregate2<<<(NN + 3) / 4, 256, 0, stream>>>(hw2, offsets, esrc, dis, bmu, blv, out);
}

// Round 3
// 566.359 us; speedup vs baseline: 1.3364x; 1.0181x over previous
//
#include <hip/hip_runtime.h>
#include <math.h>

#define NN 100000
#define NE 1250000
#define DIN 64
#define DHID 128
#define DO2 64   // concat(mu|lv)
#define DOUT 32

#define SCAN_CHUNK 1024
#define SCAN_NB ((NN + SCAN_CHUNK - 1) / SCAN_CHUNK)   // 98

typedef unsigned int uint;
typedef unsigned short ushort;

__device__ __forceinline__ ushort f2bf(float f) {
    uint u = __float_as_uint(f);
    uint r = (u + 0x7fffu + ((u >> 16) & 1u)) >> 16;   // RNE
    return (ushort)r;
}
__device__ __forceinline__ float bflo(uint p) { return __uint_as_float(p << 16); }
__device__ __forceinline__ float bfhi(uint p) { return __uint_as_float(p & 0xffff0000u); }

// ---------- small helpers ----------
__global__ void zero_two(int* a, int* b, int n) {
    int i = blockIdx.x * blockDim.x + threadIdx.x;
    if (i < n) { a[i] = 0; b[i] = 0; }
}

__global__ void count_dst(const int* __restrict__ dst, int* __restrict__ counts, int n) {
    int i = blockIdx.x * blockDim.x + threadIdx.x;
    if (i < n) atomicAdd(&counts[dst[i]], 1);
}

__global__ void compute_dis(const int* __restrict__ counts, float* __restrict__ dis, int n) {
    int i = blockIdx.x * blockDim.x + threadIdx.x;
    if (i < n) dis[i] = rsqrtf((float)counts[i] + 1.0f);  // +1 self-loop; always > 0
}

// ---------- hierarchical exclusive scan over counts[NN] ----------
__global__ __launch_bounds__(1024) void scan_phase1(const int* __restrict__ counts,
                                                    int* __restrict__ offsets,
                                                    int* __restrict__ blocksums, int n) {
    __shared__ int buf[SCAN_CHUNK];
    int tid = threadIdx.x;
    int i = blockIdx.x * SCAN_CHUNK + tid;
    int v = (i < n) ? counts[i] : 0;
    buf[tid] = v;
    __syncthreads();
    for (int off = 1; off < SCAN_CHUNK; off <<= 1) {
        int t = (tid >= off) ? buf[tid - off] : 0;
        __syncthreads();
        buf[tid] += t;
        __syncthreads();
    }
    if (i < n) offsets[i] = buf[tid] - v;            // block-local exclusive
    if (tid == SCAN_CHUNK - 1) blocksums[blockIdx.x] = buf[tid];
}

__global__ __launch_bounds__(128) void scan_phase2(int* __restrict__ blocksums, int nb) {
    __shared__ int buf[128];
    int tid = threadIdx.x;
    int v = (tid < nb) ? blocksums[tid] : 0;
    buf[tid] = v;
    __syncthreads();
    for (int off = 1; off < 128; off <<= 1) {
        int t = (tid >= off) ? buf[tid - off] : 0;
        __syncthreads();
        buf[tid] += t;
        __syncthreads();
    }
    if (tid < nb) blocksums[tid] = buf[tid] - v;     // exclusive block bases
}

__global__ __launch_bounds__(1024) void scan_phase3(int* __restrict__ offsets,
                                                    const int* __restrict__ blocksums, int n) {
    int i = blockIdx.x * SCAN_CHUNK + threadIdx.x;
    if (i < n) offsets[i] += blocksums[blockIdx.x];
    if (blockIdx.x == 0 && threadIdx.x == 0) offsets[n] = NE;  // total = E exactly
}

// scatter: build edge records {src, dis[src]} grouped by dst
__global__ void scatter_edges(const int* __restrict__ src, const int* __restrict__ dst,
                              const int* __restrict__ offsets, int* __restrict__ cursor,
                              const float* __restrict__ dis,
                              int2* __restrict__ edata, int n) {
    int i = blockIdx.x * blockDim.x + threadIdx.x;
    if (i < n) {
        int d = dst[i];
        int s = src[i];
        int pos = offsets[d] + atomicAdd(&cursor[d], 1);
        edata[pos] = make_int2(s, __float_as_int(dis[s]));
    }
}

__global__ void build_wcat(const float* __restrict__ Wmu, const float* __restrict__ Wlv,
                           float* __restrict__ Wcat) {
    int i = blockIdx.x * blockDim.x + threadIdx.x;  // 128*64
    if (i < DHID * DO2) {
        int k = i >> 6, j = i & 63;
        Wcat[i] = (j < DOUT) ? Wmu[k * DOUT + j] : Wlv[k * DOUT + (j - DOUT)];
    }
}

// ---------- GEMM1: x[N,64] @ W1[64,128] -> hw1 bf16[N,128] ----------
__global__ __launch_bounds__(256) void gemm1(const float* __restrict__ x,
                                             const float* __restrict__ W,
                                             ushort* __restrict__ out) {
    __shared__ float xs[32][65];
    __shared__ float Ws[64][128];
    int tid = threadIdx.x;
    int row0 = blockIdx.x * 32;

    for (int t = tid; t < (64 * 128) / 4; t += 256)
        ((float4*)Ws)[t] = ((const float4*)W)[t];
    for (int t = tid; t < (32 * 64) / 4; t += 256) {
        int r = t >> 4, c4 = t & 15;
        int row = row0 + r;
        float4 v = make_float4(0.f, 0.f, 0.f, 0.f);
        if (row < NN) v = ((const float4*)(x + (size_t)row * DIN))[c4];
        xs[r][c4 * 4 + 0] = v.x; xs[r][c4 * 4 + 1] = v.y;
        xs[r][c4 * 4 + 2] = v.z; xs[r][c4 * 4 + 3] = v.w;
    }
    __syncthreads();

    int r = tid >> 3;
    int c0 = (tid & 7) * 16;
    float acc[16];
#pragma unroll
    for (int j = 0; j < 16; j++) acc[j] = 0.f;
#pragma unroll
    for (int k = 0; k < 64; k++) {
        float a = xs[r][k];
#pragma unroll
        for (int j = 0; j < 16; j++) acc[j] += a * Ws[k][c0 + j];
    }
    int row = row0 + r;
    if (row < NN) {
        uint pk[8];
#pragma unroll
        for (int j = 0; j < 8; j++)
            pk[j] = (uint)f2bf(acc[2 * j]) | ((uint)f2bf(acc[2 * j + 1]) << 16);
        uint4* o = (uint4*)(out + (size_t)row * DHID + c0);
        o[0] = make_uint4(pk[0], pk[1], pk[2], pk[3]);
        o[1] = make_uint4(pk[4], pk[5], pk[6], pk[7]);
    }
}

// ---------- GEMM2: h[N,128] @ Wcat[128,64] -> hw2 bf16[N,64] ----------
__global__ __launch_bounds__(256) void gemm2(const float* __restrict__ h,
                                             const float* __restrict__ W,
                                             ushort* __restrict__ out) {
    __shared__ float hs[32][129];
    __shared__ float Ws[128][64];
    int tid = threadIdx.x;
    int row0 = blockIdx.x * 32;

    for (int t = tid; t < (128 * 64) / 4; t += 256)
        ((float4*)Ws)[t] = ((const float4*)W)[t];
    for (int t = tid; t < (32 * 128) / 4; t += 256) {
        int r = t >> 5, c4 = t & 31;
        int row = row0 + r;
        float4 v = make_float4(0.f, 0.f, 0.f, 0.f);
        if (row < NN) v = ((const float4*)(h + (size_t)row * DHID))[c4];
        hs[r][c4 * 4 + 0] = v.x; hs[r][c4 * 4 + 1] = v.y;
        hs[r][c4 * 4 + 2] = v.z; hs[r][c4 * 4 + 3] = v.w;
    }
    __syncthreads();

    int r = tid >> 3;
    int c0 = (tid & 7) * 8;
    float acc[8];
#pragma unroll
    for (int j = 0; j < 8; j++) acc[j] = 0.f;
#pragma unroll
    for (int k = 0; k < 128; k++) {
        float a = hs[r][k];
#pragma unroll
        for (int j = 0; j < 8; j++) acc[j] += a * Ws[k][c0 + j];
    }
    int row = row0 + r;
    if (row < NN) {
        uint pk[4];
#pragma unroll
        for (int j = 0; j < 4; j++)
            pk[j] = (uint)f2bf(acc[2 * j]) | ((uint)f2bf(acc[2 * j + 1]) << 16);
        *(uint4*)(out + (size_t)row * DO2 + c0) = make_uint4(pk[0], pk[1], pk[2], pk[3]);
    }
}

__device__ __forceinline__ float selu_f(float v) {
    const float scale = 1.0507009873554805f;
    const float alpha = 1.6732632423543772f;
    return scale * (v > 0.f ? v : alpha * (expf(v) - 1.f));
}

// ---------- aggregate layer 1: one wave per node, bf16x2 per lane, 4-edge unroll ----------
__global__ __launch_bounds__(256) void aggregate1(const ushort* __restrict__ hwb,
                                                  const int* __restrict__ offsets,
                                                  const int2* __restrict__ edata,
                                                  const float* __restrict__ dis,
                                                  const float* __restrict__ b,
                                                  float* __restrict__ h) {
    int wave = threadIdx.x >> 6;
    int lane = threadIdx.x & 63;
    int v = blockIdx.x * 4 + wave;
    if (v >= NN) return;
    int beg = offsets[v], end = offsets[v + 1];
    float acc0 = 0.f, acc1 = 0.f;
    for (int base = beg; base < end; base += 4) {
        int n = end - base;
        int2 r0 = edata[base];
        int2 r1 = (n > 1) ? edata[base + 1] : make_int2(0, 0);
        int2 r2 = (n > 2) ? edata[base + 2] : make_int2(0, 0);
        int2 r3 = (n > 3) ? edata[base + 3] : make_int2(0, 0);
        uint p0 = ((const uint*)(hwb + (size_t)r0.x * DHID))[lane];
        uint p1 = ((const uint*)(hwb + (size_t)r1.x * DHID))[lane];
        uint p2 = ((const uint*)(hwb + (size_t)r2.x * DHID))[lane];
        uint p3 = ((const uint*)(hwb + (size_t)r3.x * DHID))[lane];
        float c0 = __int_as_float(r0.y), c1 = __int_as_float(r1.y);
        float c2 = __int_as_float(r2.y), c3 = __int_as_float(r3.y);
        acc0 += c0 * bflo(p0) + c1 * bflo(p1) + c2 * bflo(p2) + c3 * bflo(p3);
        acc1 += c0 * bfhi(p0) + c1 * bfhi(p1) + c2 * bfhi(p2) + c3 * bfhi(p3);
    }
    float dv = dis[v];
    uint pv = ((const uint*)(hwb + (size_t)v * DHID))[lane];
    acc0 += dv * bflo(pv);
    acc1 += dv * bfhi(pv);
    float o0 = selu_f(dv * acc0 + b[2 * lane]);
    float o1 = selu_f(dv * acc1 + b[2 * lane + 1]);
    ((float2*)(h + (size_t)v * DHID))[lane] = make_float2(o0, o1);
}

// ---------- aggregate layer 2: half-wave = one edge, bf16x2/lane, 4-edge unroll ----------
__global__ __launch_bounds__(256) void aggregate2(const ushort* __restrict__ hw2b,
                                                  const int* __restrict__ offsets,
                                                  const int2* __restrict__ edata,
                                                  const float* __restrict__ dis,
                                                  const float* __restrict__ bmu,
                                                  const float* __restrict__ blv,
                                                  float* __restrict__ out) {
    int wave = threadIdx.x >> 6;
    int lane = threadIdx.x & 63;
    int half = lane >> 5;
    int l32 = lane & 31;
    int v = blockIdx.x * 4 + wave;
    if (v >= NN) return;
    int beg = offsets[v], end = offsets[v + 1];
    float acc0 = 0.f, acc1 = 0.f;
    for (int base = beg; base < end; base += 4) {
        int e0 = base + half;
        int e1 = base + 2 + half;
        int2 r0 = (e0 < end) ? edata[e0] : make_int2(0, 0);
        int2 r1 = (e1 < end) ? edata[e1] : make_int2(0, 0);
        uint p0 = ((const uint*)(hw2b + (size_t)r0.x * DO2))[l32];
        uint p1 = ((const uint*)(hw2b + (size_t)r1.x * DO2))[l32];
        float c0 = __int_as_float(r0.y), c1 = __int_as_float(r1.y);
        acc0 += c0 * bflo(p0) + c1 * bflo(p1);
        acc1 += c0 * bfhi(p0) + c1 * bfhi(p1);
    }
    acc0 += __shfl_xor(acc0, 32);
    acc1 += __shfl_xor(acc1, 32);
    if (lane < 32) {
        float dv = dis[v];
        uint pv = ((const uint*)(hw2b + (size_t)v * DO2))[l32];
        acc0 += dv * bflo(pv);
        acc1 += dv * bfhi(pv);
        float bias0 = (l32 < 16) ? bmu[2 * l32] : blv[2 * l32 - 32];
        float bias1 = (l32 < 16) ? bmu[2 * l32 + 1] : blv[2 * l32 - 31];
        float o0 = dv * acc0 + bias0;
        float o1 = dv * acc1 + bias1;
        if (l32 < 16)
            ((float2*)(out + (size_t)v * DOUT))[l32] = make_float2(o0, o1);
        else
            ((float2*)(out + (size_t)NN * DOUT + (size_t)v * DOUT))[l32 - 16] = make_float2(o0, o1);
    }
}

extern "C" void kernel_launch(void* const* d_in, const int* in_sizes, int n_in,
                              void* d_out, int out_size, void* d_ws, size_t ws_size,
                              hipStream_t stream) {
    const float* x   = (const float*)d_in[0];
    const int*   ei  = (const int*)d_in[1];
    const int*   e_src = ei;            // edge_index[0]
    const int*   e_dst = ei + NE;       // edge_index[1]
    const float* W1  = (const float*)d_in[2];
    const float* b1  = (const float*)d_in[3];
    const float* Wmu = (const float*)d_in[4];
    const float* bmu = (const float*)d_in[5];
    const float* Wlv = (const float*)d_in[6];
    const float* blv = (const float*)d_in[7];
    float* out = (float*)d_out;

    char* ws = (char*)d_ws;
    size_t off = 0;
    auto alloc = [&](size_t bytes) -> void* {
        void* p = ws + off;
        off += (bytes + 255) & ~(size_t)255;
        return p;
    };
    int*    counts    = (int*)alloc((size_t)NN * 4);
    int*    cursor    = (int*)alloc((size_t)NN * 4);
    int*    offsets   = (int*)alloc((size_t)(NN + 1) * 4);
    int2*   edata     = (int2*)alloc((size_t)NE * 8);
    int*    blocksums = (int*)alloc((size_t)SCAN_NB * 4);
    float*  dis       = (float*)alloc((size_t)NN * 4);
    float*  Wcat      = (float*)alloc((size_t)DHID * DO2 * 4);
    ushort* hw1b      = (ushort*)alloc((size_t)NN * DHID * 2);
    float*  h         = (float*)alloc((size_t)NN * DHID * 4);
    ushort* hw2b      = hw1b;  // hw1b dead after aggregate1; 12.8MB <= 25.6MB

    zero_two<<<(NN + 255) / 256, 256, 0, stream>>>(counts, cursor, NN);
    count_dst<<<(NE + 255) / 256, 256, 0, stream>>>(e_dst, counts, NE);
    compute_dis<<<(NN + 255) / 256, 256, 0, stream>>>(counts, dis, NN);
    scan_phase1<<<SCAN_NB, 1024, 0, stream>>>(counts, offsets, blocksums, NN);
    scan_phase2<<<1, 128, 0, stream>>>(blocksums, SCAN_NB);
    scan_phase3<<<SCAN_NB, 1024, 0, stream>>>(offsets, blocksums, NN);
    scatter_edges<<<(NE + 255) / 256, 256, 0, stream>>>(e_src, e_dst, offsets, cursor, dis, edata, NE);
    build_wcat<<<(DHID * DO2 + 255) / 256, 256, 0, stream>>>(Wmu, Wlv, Wcat);

    gemm1<<<(NN + 31) / 32, 256, 0, stream>>>(x, W1, hw1b);
    aggregate1<<<(NN + 3) / 4, 256, 0, stream>>>(hw1b, offsets, edata, dis, b1, h);
    gemm2<<<(NN + 31) / 32, 256, 0, stream>>>(h, Wcat, hw2b);
    aggregate2<<<(NN + 3) / 4, 256, 0, stream>>>(hw2b, offsets, edata, dis, bmu, blv, out);
}

// Round 4
// 433.313 us; speedup vs baseline: 1.7468x; 1.3070x over previous
//
#include <hip/hip_runtime.h>
#include <math.h>

#define NN 100000
#define NE 1250000
#define DIN 64
#define DHID 128
#define DO2 64   // concat(mu|lv)
#define DOUT 32

#define SCAN_CHUNK 1024
#define SCAN_NB ((NN + SCAN_CHUNK - 1) / SCAN_CHUNK)   // 98

typedef unsigned int uint;
typedef unsigned short ushort;

__device__ __forceinline__ ushort f2bf(float f) {
    uint u = __float_as_uint(f);
    uint r = (u + 0x7fffu + ((u >> 16) & 1u)) >> 16;   // RNE
    return (ushort)r;
}
__device__ __forceinline__ float bflo(uint p) { return __uint_as_float(p << 16); }
__device__ __forceinline__ float bfhi(uint p) { return __uint_as_float(p & 0xffff0000u); }

// ---------- small helpers ----------
__global__ void zero_two(int* a, int* b, int n) {
    int i = blockIdx.x * blockDim.x + threadIdx.x;
    if (i < n) { a[i] = 0; b[i] = 0; }
}

__global__ void count_dst(const int* __restrict__ dst, int* __restrict__ counts, int n) {
    int i = blockIdx.x * blockDim.x + threadIdx.x;
    if (i < n) atomicAdd(&counts[dst[i]], 1);
}

__global__ void compute_dis(const int* __restrict__ counts, float* __restrict__ dis, int n) {
    int i = blockIdx.x * blockDim.x + threadIdx.x;
    if (i < n) dis[i] = rsqrtf((float)counts[i] + 1.0f);  // +1 self-loop; always > 0
}

// ---------- hierarchical exclusive scan over counts[NN] ----------
__global__ __launch_bounds__(1024) void scan_phase1(const int* __restrict__ counts,
                                                    int* __restrict__ offsets,
                                                    int* __restrict__ blocksums, int n) {
    __shared__ int buf[SCAN_CHUNK];
    int tid = threadIdx.x;
    int i = blockIdx.x * SCAN_CHUNK + tid;
    int v = (i < n) ? counts[i] : 0;
    buf[tid] = v;
    __syncthreads();
    for (int off = 1; off < SCAN_CHUNK; off <<= 1) {
        int t = (tid >= off) ? buf[tid - off] : 0;
        __syncthreads();
        buf[tid] += t;
        __syncthreads();
    }
    if (i < n) offsets[i] = buf[tid] - v;            // block-local exclusive
    if (tid == SCAN_CHUNK - 1) blocksums[blockIdx.x] = buf[tid];
}

__global__ __launch_bounds__(128) void scan_phase2(int* __restrict__ blocksums, int nb) {
    __shared__ int buf[128];
    int tid = threadIdx.x;
    int v = (tid < nb) ? blocksums[tid] : 0;
    buf[tid] = v;
    __syncthreads();
    for (int off = 1; off < 128; off <<= 1) {
        int t = (tid >= off) ? buf[tid - off] : 0;
        __syncthreads();
        buf[tid] += t;
        __syncthreads();
    }
    if (tid < nb) blocksums[tid] = buf[tid] - v;     // exclusive block bases
}

__global__ __launch_bounds__(1024) void scan_phase3(int* __restrict__ offsets,
                                                    const int* __restrict__ blocksums, int n) {
    int i = blockIdx.x * SCAN_CHUNK + threadIdx.x;
    if (i < n) offsets[i] += blocksums[blockIdx.x];
    if (blockIdx.x == 0 && threadIdx.x == 0) offsets[n] = NE;  // total = E exactly
}

// scatter: build edge records {src, dis[src]} grouped by dst
__global__ void scatter_edges(const int* __restrict__ src, const int* __restrict__ dst,
                              const int* __restrict__ offsets, int* __restrict__ cursor,
                              const float* __restrict__ dis,
                              int2* __restrict__ edata, int n) {
    int i = blockIdx.x * blockDim.x + threadIdx.x;
    if (i < n) {
        int d = dst[i];
        int s = src[i];
        int pos = offsets[d] + atomicAdd(&cursor[d], 1);
        edata[pos] = make_int2(s, __float_as_int(dis[s]));
    }
}

__global__ void build_wcat(const float* __restrict__ Wmu, const float* __restrict__ Wlv,
                           float* __restrict__ Wcat) {
    int i = blockIdx.x * blockDim.x + threadIdx.x;  // 128*64
    if (i < DHID * DO2) {
        int k = i >> 6, j = i & 63;
        Wcat[i] = (j < DOUT) ? Wmu[k * DOUT + j] : Wlv[k * DOUT + (j - DOUT)];
    }
}

// ---------- GEMM1: x[N,64] @ W1[64,128] -> hw1 bf16[N,128] ----------
// 64-row x 128-col tile, 256 threads, 8x4 register tile, activations transposed in LDS
__global__ __launch_bounds__(256) void gemm1(const float* __restrict__ x,
                                             const float* __restrict__ W,
                                             ushort* __restrict__ out) {
    __shared__ __align__(16) float xT[DIN][64];     // [k][row]  16 KB
    __shared__ __align__(16) float Ws[DIN][DHID];   // 32 KB
    int tid = threadIdx.x;
    int row0 = blockIdx.x * 64;

    for (int t = tid; t < (DIN * DHID) / 4; t += 256)
        ((float4*)Ws)[t] = ((const float4*)W)[t];

    int rr = tid & 63;
    int kq = tid >> 6;               // 0..3
    int grow = row0 + rr;
    for (int k0 = kq * 4; k0 < DIN; k0 += 16) {
        float4 v = make_float4(0.f, 0.f, 0.f, 0.f);
        if (grow < NN) v = *(const float4*)(x + (size_t)grow * DIN + k0);
        xT[k0 + 0][rr] = v.x; xT[k0 + 1][rr] = v.y;
        xT[k0 + 2][rr] = v.z; xT[k0 + 3][rr] = v.w;
    }
    __syncthreads();

    int tx = tid & 31;               // col group
    int ty = tid >> 5;               // 0..7 row group
    int c0 = tx * 4;
    int r0 = ty * 8;
    float acc[8][4];
#pragma unroll
    for (int i = 0; i < 8; i++)
#pragma unroll
        for (int j = 0; j < 4; j++) acc[i][j] = 0.f;

#pragma unroll 4
    for (int k = 0; k < DIN; k++) {
        float4 a0 = *(const float4*)&xT[k][r0];
        float4 a1 = *(const float4*)&xT[k][r0 + 4];
        float4 w  = *(const float4*)&Ws[k][c0];
        float av[8] = {a0.x, a0.y, a0.z, a0.w, a1.x, a1.y, a1.z, a1.w};
        float wv[4] = {w.x, w.y, w.z, w.w};
#pragma unroll
        for (int i = 0; i < 8; i++)
#pragma unroll
            for (int j = 0; j < 4; j++) acc[i][j] += av[i] * wv[j];
    }

#pragma unroll
    for (int i = 0; i < 8; i++) {
        int orow = row0 + r0 + i;
        if (orow < NN) {
            uint p0 = (uint)f2bf(acc[i][0]) | ((uint)f2bf(acc[i][1]) << 16);
            uint p1 = (uint)f2bf(acc[i][2]) | ((uint)f2bf(acc[i][3]) << 16);
            *(uint2*)(out + (size_t)orow * DHID + c0) = make_uint2(p0, p1);
        }
    }
}

// ---------- GEMM2: h[N,128] @ Wcat[128,64] -> hw2 bf16[N,64] ----------
// 64-row x 64-col tile, 256 threads, 4x4 register tile
__global__ __launch_bounds__(256) void gemm2(const float* __restrict__ h,
                                             const float* __restrict__ W,
                                             ushort* __restrict__ out) {
    __shared__ __align__(16) float hsT[DHID][64];   // [k][row] 32 KB
    __shared__ __align__(16) float Ws[DHID][DO2];   // 32 KB
    int tid = threadIdx.x;
    int row0 = blockIdx.x * 64;

    for (int t = tid; t < (DHID * DO2) / 4; t += 256)
        ((float4*)Ws)[t] = ((const float4*)W)[t];

    int rr = tid & 63;
    int kq = tid >> 6;               // 0..3
    int grow = row0 + rr;
    for (int k0 = kq * 4; k0 < DHID; k0 += 16) {
        float4 v = make_float4(0.f, 0.f, 0.f, 0.f);
        if (grow < NN) v = *(const float4*)(h + (size_t)grow * DHID + k0);
        hsT[k0 + 0][rr] = v.x; hsT[k0 + 1][rr] = v.y;
        hsT[k0 + 2][rr] = v.z; hsT[k0 + 3][rr] = v.w;
    }
    __syncthreads();

    int tx = tid & 15;
    int ty = tid >> 4;               // 0..15
    int c0 = tx * 4;
    int r0 = ty * 4;
    float acc[4][4];
#pragma unroll
    for (int i = 0; i < 4; i++)
#pragma unroll
        for (int j = 0; j < 4; j++) acc[i][j] = 0.f;

#pragma unroll 4
    for (int k = 0; k < DHID; k++) {
        float4 a = *(const float4*)&hsT[k][r0];
        float4 w = *(const float4*)&Ws[k][c0];
        float av[4] = {a.x, a.y, a.z, a.w};
        float wv[4] = {w.x, w.y, w.z, w.w};
#pragma unroll
        for (int i = 0; i < 4; i++)
#pragma unroll
            for (int j = 0; j < 4; j++) acc[i][j] += av[i] * wv[j];
    }

#pragma unroll
    for (int i = 0; i < 4; i++) {
        int orow = row0 + r0 + i;
        if (orow < NN) {
            uint p0 = (uint)f2bf(acc[i][0]) | ((uint)f2bf(acc[i][1]) << 16);
            uint p1 = (uint)f2bf(acc[i][2]) | ((uint)f2bf(acc[i][3]) << 16);
            *(uint2*)(out + (size_t)orow * DO2 + c0) = make_uint2(p0, p1);
        }
    }
}

__device__ __forceinline__ float selu_f(float v) {
    const float scale = 1.0507009873554805f;
    const float alpha = 1.6732632423543772f;
    return scale * (v > 0.f ? v : alpha * (expf(v) - 1.f));
}

// ---------- aggregate layer 1: one wave per node, bf16x2 per lane, 4-edge unroll ----------
__global__ __launch_bounds__(256) void aggregate1(const ushort* __restrict__ hwb,
                                                  const int* __restrict__ offsets,
                                                  const int2* __restrict__ edata,
                                                  const float* __restrict__ dis,
                                                  const float* __restrict__ b,
                                                  float* __restrict__ h) {
    int wave = threadIdx.x >> 6;
    int lane = threadIdx.x & 63;
    int v = blockIdx.x * 4 + wave;
    if (v >= NN) return;
    int beg = offsets[v], end = offsets[v + 1];
    float acc0 = 0.f, acc1 = 0.f;
    for (int base = beg; base < end; base += 4) {
        int n = end - base;
        int2 r0 = edata[base];
        int2 r1 = (n > 1) ? edata[base + 1] : make_int2(0, 0);
        int2 r2 = (n > 2) ? edata[base + 2] : make_int2(0, 0);
        int2 r3 = (n > 3) ? edata[base + 3] : make_int2(0, 0);
        uint p0 = ((const uint*)(hwb + (size_t)r0.x * DHID))[lane];
        uint p1 = ((const uint*)(hwb + (size_t)r1.x * DHID))[lane];
        uint p2 = ((const uint*)(hwb + (size_t)r2.x * DHID))[lane];
        uint p3 = ((const uint*)(hwb + (size_t)r3.x * DHID))[lane];
        float c0 = __int_as_float(r0.y), c1 = __int_as_float(r1.y);
        float c2 = __int_as_float(r2.y), c3 = __int_as_float(r3.y);
        acc0 += c0 * bflo(p0) + c1 * bflo(p1) + c2 * bflo(p2) + c3 * bflo(p3);
        acc1 += c0 * bfhi(p0) + c1 * bfhi(p1) + c2 * bfhi(p2) + c3 * bfhi(p3);
    }
    float dv = dis[v];
    uint pv = ((const uint*)(hwb + (size_t)v * DHID))[lane];
    acc0 += dv * bflo(pv);
    acc1 += dv * bfhi(pv);
    float o0 = selu_f(dv * acc0 + b[2 * lane]);
    float o1 = selu_f(dv * acc1 + b[2 * lane + 1]);
    ((float2*)(h + (size_t)v * DHID))[lane] = make_float2(o0, o1);
}

// ---------- aggregate layer 2: half-wave = one edge, bf16x2/lane, 4-edge unroll ----------
__global__ __launch_bounds__(256) void aggregate2(const ushort* __restrict__ hw2b,
                                                  const int* __restrict__ offsets,
                                                  const int2* __restrict__ edata,
                                                  const float* __restrict__ dis,
                                                  const float* __restrict__ bmu,
                                                  const float* __restrict__ blv,
                                                  float* __restrict__ out) {
    int wave = threadIdx.x >> 6;
    int lane = threadIdx.x & 63;
    int half = lane >> 5;
    int l32 = lane & 31;
    int v = blockIdx.x * 4 + wave;
    if (v >= NN) return;
    int beg = offsets[v], end = offsets[v + 1];
    float acc0 = 0.f, acc1 = 0.f;
    for (int base = beg; base < end; base += 4) {
        int e0 = base + half;
        int e1 = base + 2 + half;
        int2 r0 = (e0 < end) ? edata[e0] : make_int2(0, 0);
        int2 r1 = (e1 < end) ? edata[e1] : make_int2(0, 0);
        uint p0 = ((const uint*)(hw2b + (size_t)r0.x * DO2))[l32];
        uint p1 = ((const uint*)(hw2b + (size_t)r1.x * DO2))[l32];
        float c0 = __int_as_float(r0.y), c1 = __int_as_float(r1.y);
        acc0 += c0 * bflo(p0) + c1 * bflo(p1);
        acc1 += c0 * bfhi(p0) + c1 * bfhi(p1);
    }
    acc0 += __shfl_xor(acc0, 32);
    acc1 += __shfl_xor(acc1, 32);
    if (lane < 32) {
        float dv = dis[v];
        uint pv = ((const uint*)(hw2b + (size_t)v * DO2))[l32];
        acc0 += dv * bflo(pv);
        acc1 += dv * bfhi(pv);
        float bias0 = (l32 < 16) ? bmu[2 * l32] : blv[2 * l32 - 32];
        float bias1 = (l32 < 16) ? bmu[2 * l32 + 1] : blv[2 * l32 - 31];
        float o0 = dv * acc0 + bias0;
        float o1 = dv * acc1 + bias1;
        if (l32 < 16)
            ((float2*)(out + (size_t)v * DOUT))[l32] = make_float2(o0, o1);
        else
            ((float2*)(out + (size_t)NN * DOUT + (size_t)v * DOUT))[l32 - 16] = make_float2(o0, o1);
    }
}

extern "C" void kernel_launch(void* const* d_in, const int* in_sizes, int n_in,
                              void* d_out, int out_size, void* d_ws, size_t ws_size,
                              hipStream_t stream) {
    const float* x   = (const float*)d_in[0];
    const int*   ei  = (const int*)d_in[1];
    const int*   e_src = ei;            // edge_index[0]
    const int*   e_dst = ei + NE;       // edge_index[1]
    const float* W1  = (const float*)d_in[2];
    const float* b1  = (const float*)d_in[3];
    const float* Wmu = (const float*)d_in[4];
    const float* bmu = (const float*)d_in[5];
    const float* Wlv = (const float*)d_in[6];
    const float* blv = (const float*)d_in[7];
    float* out = (float*)d_out;

    char* ws = (char*)d_ws;
    size_t off = 0;
    auto alloc = [&](size_t bytes) -> void* {
        void* p = ws + off;
        off += (bytes + 255) & ~(size_t)255;
        return p;
    };
    int*    counts    = (int*)alloc((size_t)NN * 4);
    int*    cursor    = (int*)alloc((size_t)NN * 4);
    int*    offsets   = (int*)alloc((size_t)(NN + 1) * 4);
    int2*   edata     = (int2*)alloc((size_t)NE * 8);
    int*    blocksums = (int*)alloc((size_t)SCAN_NB * 4);
    float*  dis       = (float*)alloc((size_t)NN * 4);
    float*  Wcat      = (float*)alloc((size_t)DHID * DO2 * 4);
    ushort* hw1b      = (ushort*)alloc((size_t)NN * DHID * 2);
    float*  h         = (float*)alloc((size_t)NN * DHID * 4);
    ushort* hw2b      = hw1b;  // hw1b dead after aggregate1; 12.8MB <= 25.6MB

    zero_two<<<(NN + 255) / 256, 256, 0, stream>>>(counts, cursor, NN);
    count_dst<<<(NE + 255) / 256, 256, 0, stream>>>(e_dst, counts, NE);
    compute_dis<<<(NN + 255) / 256, 256, 0, stream>>>(counts, dis, NN);
    scan_phase1<<<SCAN_NB, 1024, 0, stream>>>(counts, offsets, blocksums, NN);
    scan_phase2<<<1, 128, 0, stream>>>(blocksums, SCAN_NB);
    scan_phase3<<<SCAN_NB, 1024, 0, stream>>>(offsets, blocksums, NN);
    scatter_edges<<<(NE + 255) / 256, 256, 0, stream>>>(e_src, e_dst, offsets, cursor, dis, edata, NE);
    build_wcat<<<(DHID * DO2 + 255) / 256, 256, 0, stream>>>(Wmu, Wlv, Wcat);

    int gblocks = (NN + 63) / 64;
    gemm1<<<gblocks, 256, 0, stream>>>(x, W1, hw1b);
    aggregate1<<<(NN + 3) / 4, 256, 0, stream>>>(hw1b, offsets, edata, dis, b1, h);
    gemm2<<<gblocks, 256, 0, stream>>>(h, Wcat, hw2b);
    aggregate2<<<(NN + 3) / 4, 256, 0, stream>>>(hw2b, offsets, edata, dis, bmu, blv, out);
}

// Round 5
// 400.343 us; speedup vs baseline: 1.8906x; 1.0824x over previous
//
#include <hip/hip_runtime.h>
#include <math.h>

#define NN 100000
#define NE 1250000
#define DIN 64
#define DHID 128
#define DO2 64   // concat(mu|lv)
#define DOUT 32

#define SCAN_CHUNK 1024
#define SCAN_NB ((NN + SCAN_CHUNK - 1) / SCAN_CHUNK)   // 98

typedef unsigned int uint;
typedef unsigned short ushort;

__device__ __forceinline__ ushort f2bf(float f) {
    uint u = __float_as_uint(f);
    uint r = (u + 0x7fffu + ((u >> 16) & 1u)) >> 16;   // RNE
    return (ushort)r;
}
__device__ __forceinline__ float bflo(uint p) { return __uint_as_float(p << 16); }
__device__ __forceinline__ float bfhi(uint p) { return __uint_as_float(p & 0xffff0000u); }

// ---------- small helpers ----------
__global__ void zero_two(int* a, int* b, int n) {
    int i = blockIdx.x * blockDim.x + threadIdx.x;
    if (i < n) { a[i] = 0; b[i] = 0; }
}

__global__ void count_dst(const int* __restrict__ dst, int* __restrict__ counts, int n) {
    int i = blockIdx.x * blockDim.x + threadIdx.x;
    if (i < n) atomicAdd(&counts[dst[i]], 1);
}

__global__ void compute_dis(const int* __restrict__ counts, float* __restrict__ dis, int n) {
    int i = blockIdx.x * blockDim.x + threadIdx.x;
    if (i < n) dis[i] = rsqrtf((float)counts[i] + 1.0f);  // +1 self-loop; always > 0
}

// cast x -> bf16 (packed)
__global__ void cast_x(const float* __restrict__ x, uint* __restrict__ xb, int npairs) {
    int i = blockIdx.x * blockDim.x + threadIdx.x;
    if (i < npairs) {
        float2 v = ((const float2*)x)[i];
        xb[i] = (uint)f2bf(v.x) | ((uint)f2bf(v.y) << 16);
    }
}

// ---------- hierarchical exclusive scan over counts[NN] ----------
__global__ __launch_bounds__(1024) void scan_phase1(const int* __restrict__ counts,
                                                    int* __restrict__ offsets,
                                                    int* __restrict__ blocksums, int n) {
    __shared__ int buf[SCAN_CHUNK];
    int tid = threadIdx.x;
    int i = blockIdx.x * SCAN_CHUNK + tid;
    int v = (i < n) ? counts[i] : 0;
    buf[tid] = v;
    __syncthreads();
    for (int off = 1; off < SCAN_CHUNK; off <<= 1) {
        int t = (tid >= off) ? buf[tid - off] : 0;
        __syncthreads();
        buf[tid] += t;
        __syncthreads();
    }
    if (i < n) offsets[i] = buf[tid] - v;            // block-local exclusive
    if (tid == SCAN_CHUNK - 1) blocksums[blockIdx.x] = buf[tid];
}

__global__ __launch_bounds__(128) void scan_phase2(int* __restrict__ blocksums, int nb) {
    __shared__ int buf[128];
    int tid = threadIdx.x;
    int v = (tid < nb) ? blocksums[tid] : 0;
    buf[tid] = v;
    __syncthreads();
    for (int off = 1; off < 128; off <<= 1) {
        int t = (tid >= off) ? buf[tid - off] : 0;
        __syncthreads();
        buf[tid] += t;
        __syncthreads();
    }
    if (tid < nb) blocksums[tid] = buf[tid] - v;     // exclusive block bases
}

__global__ __launch_bounds__(1024) void scan_phase3(int* __restrict__ offsets,
                                                    const int* __restrict__ blocksums, int n) {
    int i = blockIdx.x * SCAN_CHUNK + threadIdx.x;
    if (i < n) offsets[i] += blocksums[blockIdx.x];
    if (blockIdx.x == 0 && threadIdx.x == 0) offsets[n] = NE;  // total = E exactly
}

// scatter: build edge records {src, dis[src]} grouped by dst
__global__ void scatter_edges(const int* __restrict__ src, const int* __restrict__ dst,
                              const int* __restrict__ offsets, int* __restrict__ cursor,
                              const float* __restrict__ dis,
                              int2* __restrict__ edata, int n) {
    int i = blockIdx.x * blockDim.x + threadIdx.x;
    if (i < n) {
        int d = dst[i];
        int s = src[i];
        int pos = offsets[d] + atomicAdd(&cursor[d], 1);
        edata[pos] = make_int2(s, __float_as_int(dis[s]));
    }
}

__global__ void build_wcat(const float* __restrict__ Wmu, const float* __restrict__ Wlv,
                           float* __restrict__ Wcat) {
    int i = blockIdx.x * blockDim.x + threadIdx.x;  // 128*64
    if (i < DHID * DO2) {
        int k = i >> 6, j = i & 63;
        Wcat[i] = (j < DOUT) ? Wmu[k * DOUT + j] : Wlv[k * DOUT + (j - DOUT)];
    }
}

// ---------- aggregateX: ax[v] = dis_v * (sum_e dis_s * xb[s] + dis_v * xb[v])  [N,64] f32
// one wave per node, half-wave (32 lanes) per edge, 8-edge unroll
__global__ __launch_bounds__(256) void aggregateX(const uint* __restrict__ xb,   // bf16x2 [N,32]
                                                  const int* __restrict__ offsets,
                                                  const int2* __restrict__ edata,
                                                  const float* __restrict__ dis,
                                                  float* __restrict__ ax) {
    int wave = threadIdx.x >> 6;
    int lane = threadIdx.x & 63;
    int half = lane >> 5;
    int l32 = lane & 31;
    int v = blockIdx.x * 4 + wave;
    if (v >= NN) return;
    int beg = offsets[v], end = offsets[v + 1];
    float acc0 = 0.f, acc1 = 0.f;
    for (int base = beg; base < end; base += 8) {
        int e0 = base + half, e1 = base + 2 + half, e2 = base + 4 + half, e3 = base + 6 + half;
        int2 r0 = (e0 < end) ? edata[e0] : make_int2(0, 0);
        int2 r1 = (e1 < end) ? edata[e1] : make_int2(0, 0);
        int2 r2 = (e2 < end) ? edata[e2] : make_int2(0, 0);
        int2 r3 = (e3 < end) ? edata[e3] : make_int2(0, 0);
        uint p0 = xb[(size_t)r0.x * 32 + l32];
        uint p1 = xb[(size_t)r1.x * 32 + l32];
        uint p2 = xb[(size_t)r2.x * 32 + l32];
        uint p3 = xb[(size_t)r3.x * 32 + l32];
        float c0 = __int_as_float(r0.y), c1 = __int_as_float(r1.y);
        float c2 = __int_as_float(r2.y), c3 = __int_as_float(r3.y);
        acc0 += c0 * bflo(p0) + c1 * bflo(p1) + c2 * bflo(p2) + c3 * bflo(p3);
        acc1 += c0 * bfhi(p0) + c1 * bfhi(p1) + c2 * bfhi(p2) + c3 * bfhi(p3);
    }
    acc0 += __shfl_xor(acc0, 32);
    acc1 += __shfl_xor(acc1, 32);
    if (lane < 32) {
        float dv = dis[v];
        uint pv = xb[(size_t)v * 32 + l32];
        acc0 += dv * bflo(pv);
        acc1 += dv * bfhi(pv);
        ((float2*)(ax + (size_t)v * DIN))[l32] = make_float2(dv * acc0, dv * acc1);
    }
}

__device__ __forceinline__ float selu_f(float v) {
    const float scale = 1.0507009873554805f;
    const float alpha = 1.6732632423543772f;
    return scale * (v > 0.f ? v : alpha * (expf(v) - 1.f));
}

// ---------- GEMM1: ax[N,64] @ W1[64,128] + b1, selu -> h bf16[N,128] ----------
__global__ __launch_bounds__(256) void gemm1(const float* __restrict__ ax,
                                             const float* __restrict__ W,
                                             const float* __restrict__ b,
                                             ushort* __restrict__ out) {
    __shared__ __align__(16) float xT[DIN][64];     // [k][row]  16 KB
    __shared__ __align__(16) float Ws[DIN][DHID];   // 32 KB
    __shared__ __align__(16) float Bs[DHID];
    int tid = threadIdx.x;
    int row0 = blockIdx.x * 64;

    for (int t = tid; t < (DIN * DHID) / 4; t += 256)
        ((float4*)Ws)[t] = ((const float4*)W)[t];
    if (tid < DHID / 4) ((float4*)Bs)[tid] = ((const float4*)b)[tid];

    int rr = tid & 63;
    int kq = tid >> 6;               // 0..3
    int grow = row0 + rr;
    for (int k0 = kq * 4; k0 < DIN; k0 += 16) {
        float4 v = make_float4(0.f, 0.f, 0.f, 0.f);
        if (grow < NN) v = *(const float4*)(ax + (size_t)grow * DIN + k0);
        xT[k0 + 0][rr] = v.x; xT[k0 + 1][rr] = v.y;
        xT[k0 + 2][rr] = v.z; xT[k0 + 3][rr] = v.w;
    }
    __syncthreads();

    int tx = tid & 31;               // col group
    int ty = tid >> 5;               // 0..7 row group
    int c0 = tx * 4;
    int r0 = ty * 8;
    float acc[8][4];
#pragma unroll
    for (int i = 0; i < 8; i++)
#pragma unroll
        for (int j = 0; j < 4; j++) acc[i][j] = 0.f;

#pragma unroll 4
    for (int k = 0; k < DIN; k++) {
        float4 a0 = *(const float4*)&xT[k][r0];
        float4 a1 = *(const float4*)&xT[k][r0 + 4];
        float4 w  = *(const float4*)&Ws[k][c0];
        float av[8] = {a0.x, a0.y, a0.z, a0.w, a1.x, a1.y, a1.z, a1.w};
        float wv[4] = {w.x, w.y, w.z, w.w};
#pragma unroll
        for (int i = 0; i < 8; i++)
#pragma unroll
            for (int j = 0; j < 4; j++) acc[i][j] += av[i] * wv[j];
    }

    float4 bb = *(const float4*)&Bs[c0];
    float bv[4] = {bb.x, bb.y, bb.z, bb.w};
#pragma unroll
    for (int i = 0; i < 8; i++) {
        int orow = row0 + r0 + i;
        if (orow < NN) {
            float o0 = selu_f(acc[i][0] + bv[0]);
            float o1 = selu_f(acc[i][1] + bv[1]);
            float o2 = selu_f(acc[i][2] + bv[2]);
            float o3 = selu_f(acc[i][3] + bv[3]);
            uint p0 = (uint)f2bf(o0) | ((uint)f2bf(o1) << 16);
            uint p1 = (uint)f2bf(o2) | ((uint)f2bf(o3) << 16);
            *(uint2*)(out + (size_t)orow * DHID + c0) = make_uint2(p0, p1);
        }
    }
}

// ---------- GEMM2: h bf16[N,128] @ Wcat[128,64] -> hw2 bf16[N,64] ----------
__global__ __launch_bounds__(256) void gemm2(const ushort* __restrict__ h,
                                             const float* __restrict__ W,
                                             ushort* __restrict__ out) {
    __shared__ __align__(16) float hsT[DHID][64];   // [k][row] 32 KB
    __shared__ __align__(16) float Ws[DHID][DO2];   // 32 KB
    int tid = threadIdx.x;
    int row0 = blockIdx.x * 64;

    for (int t = tid; t < (DHID * DO2) / 4; t += 256)
        ((float4*)Ws)[t] = ((const float4*)W)[t];

    int rr = tid & 63;
    int kq = tid >> 6;               // 0..3
    int grow = row0 + rr;
    for (int k0 = kq * 8; k0 < DHID; k0 += 32) {
        uint4 pv = make_uint4(0, 0, 0, 0);
        if (grow < NN) pv = *(const uint4*)(h + (size_t)grow * DHID + k0);
        hsT[k0 + 0][rr] = bflo(pv.x); hsT[k0 + 1][rr] = bfhi(pv.x);
        hsT[k0 + 2][rr] = bflo(pv.y); hsT[k0 + 3][rr] = bfhi(pv.y);
        hsT[k0 + 4][rr] = bflo(pv.z); hsT[k0 + 5][rr] = bfhi(pv.z);
        hsT[k0 + 6][rr] = bflo(pv.w); hsT[k0 + 7][rr] = bfhi(pv.w);
    }
    __syncthreads();

    int tx = tid & 15;
    int ty = tid >> 4;               // 0..15
    int c0 = tx * 4;
    int r0 = ty * 4;
    float acc[4][4];
#pragma unroll
    for (int i = 0; i < 4; i++)
#pragma unroll
        for (int j = 0; j < 4; j++) acc[i][j] = 0.f;

#pragma unroll 4
    for (int k = 0; k < DHID; k++) {
        float4 a = *(const float4*)&hsT[k][r0];
        float4 w = *(const float4*)&Ws[k][c0];
        float av[4] = {a.x, a.y, a.z, a.w};
        float wv[4] = {w.x, w.y, w.z, w.w};
#pragma unroll
        for (int i = 0; i < 4; i++)
#pragma unroll
            for (int j = 0; j < 4; j++) acc[i][j] += av[i] * wv[j];
    }

#pragma unroll
    for (int i = 0; i < 4; i++) {
        int orow = row0 + r0 + i;
        if (orow < NN) {
            uint p0 = (uint)f2bf(acc[i][0]) | ((uint)f2bf(acc[i][1]) << 16);
            uint p1 = (uint)f2bf(acc[i][2]) | ((uint)f2bf(acc[i][3]) << 16);
            *(uint2*)(out + (size_t)orow * DO2 + c0) = make_uint2(p0, p1);
        }
    }
}

// ---------- aggregate layer 2: half-wave = one edge, bf16x2/lane, 8-edge unroll ----------
__global__ __launch_bounds__(256) void aggregate2(const ushort* __restrict__ hw2b,
                                                  const int* __restrict__ offsets,
                                                  const int2* __restrict__ edata,
                                                  const float* __restrict__ dis,
                                                  const float* __restrict__ bmu,
                                                  const float* __restrict__ blv,
                                                  float* __restrict__ out) {
    int wave = threadIdx.x >> 6;
    int lane = threadIdx.x & 63;
    int half = lane >> 5;
    int l32 = lane & 31;
    int v = blockIdx.x * 4 + wave;
    if (v >= NN) return;
    int beg = offsets[v], end = offsets[v + 1];
    float acc0 = 0.f, acc1 = 0.f;
    for (int base = beg; base < end; base += 8) {
        int e0 = base + half, e1 = base + 2 + half, e2 = base + 4 + half, e3 = base + 6 + half;
        int2 r0 = (e0 < end) ? edata[e0] : make_int2(0, 0);
        int2 r1 = (e1 < end) ? edata[e1] : make_int2(0, 0);
        int2 r2 = (e2 < end) ? edata[e2] : make_int2(0, 0);
        int2 r3 = (e3 < end) ? edata[e3] : make_int2(0, 0);
        uint p0 = ((const uint*)hw2b)[(size_t)r0.x * 32 + l32];
        uint p1 = ((const uint*)hw2b)[(size_t)r1.x * 32 + l32];
        uint p2 = ((const uint*)hw2b)[(size_t)r2.x * 32 + l32];
        uint p3 = ((const uint*)hw2b)[(size_t)r3.x * 32 + l32];
        float c0 = __int_as_float(r0.y), c1 = __int_as_float(r1.y);
        float c2 = __int_as_float(r2.y), c3 = __int_as_float(r3.y);
        acc0 += c0 * bflo(p0) + c1 * bflo(p1) + c2 * bflo(p2) + c3 * bflo(p3);
        acc1 += c0 * bfhi(p0) + c1 * bfhi(p1) + c2 * bfhi(p2) + c3 * bfhi(p3);
    }
    acc0 += __shfl_xor(acc0, 32);
    acc1 += __shfl_xor(acc1, 32);
    if (lane < 32) {
        float dv = dis[v];
        uint pv = ((const uint*)hw2b)[(size_t)v * 32 + l32];
        acc0 += dv * bflo(pv);
        acc1 += dv * bfhi(pv);
        float bias0 = (l32 < 16) ? bmu[2 * l32] : blv[2 * l32 - 32];
        float bias1 = (l32 < 16) ? bmu[2 * l32 + 1] : blv[2 * l32 - 31];
        float o0 = dv * acc0 + bias0;
        float o1 = dv * acc1 + bias1;
        if (l32 < 16)
            ((float2*)(out + (size_t)v * DOUT))[l32] = make_float2(o0, o1);
        else
            ((float2*)(out + (size_t)NN * DOUT + (size_t)v * DOUT))[l32 - 16] = make_float2(o0, o1);
    }
}

extern "C" void kernel_launch(void* const* d_in, const int* in_sizes, int n_in,
                              void* d_out, int out_size, void* d_ws, size_t ws_size,
                              hipStream_t stream) {
    const float* x   = (const float*)d_in[0];
    const int*   ei  = (const int*)d_in[1];
    const int*   e_src = ei;            // edge_index[0]
    const int*   e_dst = ei + NE;       // edge_index[1]
    const float* W1  = (const float*)d_in[2];
    const float* b1  = (const float*)d_in[3];
    const float* Wmu = (const float*)d_in[4];
    const float* bmu = (const float*)d_in[5];
    const float* Wlv = (const float*)d_in[6];
    const float* blv = (const float*)d_in[7];
    float* out = (float*)d_out;

    char* ws = (char*)d_ws;
    size_t off = 0;
    auto alloc = [&](size_t bytes) -> void* {
        void* p = ws + off;
        off += (bytes + 255) & ~(size_t)255;
        return p;
    };
    int*    counts    = (int*)alloc((size_t)NN * 4);
    int*    cursor    = (int*)alloc((size_t)NN * 4);
    int*    offsets   = (int*)alloc((size_t)(NN + 1) * 4);
    int2*   edata     = (int2*)alloc((size_t)NE * 8);
    int*    blocksums = (int*)alloc((size_t)SCAN_NB * 4);
    float*  dis       = (float*)alloc((size_t)NN * 4);
    float*  Wcat      = (float*)alloc((size_t)DHID * DO2 * 4);
    uint*   xb        = (uint*)alloc((size_t)NN * DIN * 2);     // bf16 x, 12.8 MB
    float*  ax        = (float*)alloc((size_t)NN * DIN * 4);    // 25.6 MB
    ushort* h         = (ushort*)alloc((size_t)NN * DHID * 2);  // bf16 h, 25.6 MB
    ushort* hw2b      = (ushort*)xb;   // xb dead after aggregateX; 12.8 MB fits

    zero_two<<<(NN + 255) / 256, 256, 0, stream>>>(counts, cursor, NN);
    count_dst<<<(NE + 255) / 256, 256, 0, stream>>>(e_dst, counts, NE);
    compute_dis<<<(NN + 255) / 256, 256, 0, stream>>>(counts, dis, NN);
    scan_phase1<<<SCAN_NB, 1024, 0, stream>>>(counts, offsets, blocksums, NN);
    scan_phase2<<<1, 128, 0, stream>>>(blocksums, SCAN_NB);
    scan_phase3<<<SCAN_NB, 1024, 0, stream>>>(offsets, blocksums, NN);
    scatter_edges<<<(NE + 255) / 256, 256, 0, stream>>>(e_src, e_dst, offsets, cursor, dis, edata, NE);
    build_wcat<<<(DHID * DO2 + 255) / 256, 256, 0, stream>>>(Wmu, Wlv, Wcat);
    cast_x<<<((NN * DIN / 2) + 255) / 256, 256, 0, stream>>>(x, xb, NN * DIN / 2);

    int gblocks = (NN + 63) / 64;
    aggregateX<<<(NN + 3) / 4, 256, 0, stream>>>(xb, offsets, edata, dis, ax);
    gemm1<<<gblocks, 256, 0, stream>>>(ax, W1, b1, h);
    gemm2<<<gblocks, 256, 0, stream>>>(h, Wcat, hw2b);
    aggregate2<<<(NN + 3) / 4, 256, 0, stream>>>(hw2b, offsets, edata, dis, bmu, blv, out);
}

// Round 6
// 367.244 us; speedup vs baseline: 2.0610x; 1.0901x over previous
//
#include <hip/hip_runtime.h>
#include <math.h>

#define NN 100000
#define NE 1250000
#define DIN 64
#define DHID 128
#define DO2 64   // concat(mu|lv)
#define DOUT 32

#define SCAN_CHUNK 1024
#define SCAN_NB ((NN + SCAN_CHUNK - 1) / SCAN_CHUNK)   // 98

typedef unsigned int uint;
typedef unsigned short ushort;

__device__ __forceinline__ ushort f2bf(float f) {
    uint u = __float_as_uint(f);
    uint r = (u + 0x7fffu + ((u >> 16) & 1u)) >> 16;   // RNE
    return (ushort)r;
}
__device__ __forceinline__ uint pack2(float a, float b) {
    return (uint)f2bf(a) | ((uint)f2bf(b) << 16);
}
__device__ __forceinline__ float bflo(uint p) { return __uint_as_float(p << 16); }
__device__ __forceinline__ float bfhi(uint p) { return __uint_as_float(p & 0xffff0000u); }

// ---------- small helpers ----------
__global__ void zero_two(int* a, int* b, int n) {
    int i = blockIdx.x * blockDim.x + threadIdx.x;
    if (i < n) { a[i] = 0; b[i] = 0; }
}

__global__ void count_dst(const int* __restrict__ dst, int* __restrict__ counts, int n) {
    int i = blockIdx.x * blockDim.x + threadIdx.x;
    if (i < n) atomicAdd(&counts[dst[i]], 1);
}

__global__ void compute_dis(const int* __restrict__ counts, float* __restrict__ dis, int n) {
    int i = blockIdx.x * blockDim.x + threadIdx.x;
    if (i < n) dis[i] = rsqrtf((float)counts[i] + 1.0f);  // +1 self-loop; always > 0
}

// cast x -> bf16 (packed)
__global__ void cast_x(const float* __restrict__ x, uint* __restrict__ xb, int npairs) {
    int i = blockIdx.x * blockDim.x + threadIdx.x;
    if (i < npairs) {
        float2 v = ((const float2*)x)[i];
        xb[i] = pack2(v.x, v.y);
    }
}

// ---------- hierarchical exclusive scan over counts[NN] ----------
__global__ __launch_bounds__(1024) void scan_phase1(const int* __restrict__ counts,
                                                    int* __restrict__ offsets,
                                                    int* __restrict__ blocksums, int n) {
    __shared__ int buf[SCAN_CHUNK];
    int tid = threadIdx.x;
    int i = blockIdx.x * SCAN_CHUNK + tid;
    int v = (i < n) ? counts[i] : 0;
    buf[tid] = v;
    __syncthreads();
    for (int off = 1; off < SCAN_CHUNK; off <<= 1) {
        int t = (tid >= off) ? buf[tid - off] : 0;
        __syncthreads();
        buf[tid] += t;
        __syncthreads();
    }
    if (i < n) offsets[i] = buf[tid] - v;            // block-local exclusive
    if (tid == SCAN_CHUNK - 1) blocksums[blockIdx.x] = buf[tid];
}

__global__ __launch_bounds__(128) void scan_phase2(int* __restrict__ blocksums, int nb) {
    __shared__ int buf[128];
    int tid = threadIdx.x;
    int v = (tid < nb) ? blocksums[tid] : 0;
    buf[tid] = v;
    __syncthreads();
    for (int off = 1; off < 128; off <<= 1) {
        int t = (tid >= off) ? buf[tid - off] : 0;
        __syncthreads();
        buf[tid] += t;
        __syncthreads();
    }
    if (tid < nb) blocksums[tid] = buf[tid] - v;     // exclusive block bases
}

__global__ __launch_bounds__(1024) void scan_phase3(int* __restrict__ offsets,
                                                    const int* __restrict__ blocksums, int n) {
    int i = blockIdx.x * SCAN_CHUNK + threadIdx.x;
    if (i < n) offsets[i] += blocksums[blockIdx.x];
    if (blockIdx.x == 0 && threadIdx.x == 0) offsets[n] = NE;  // total = E exactly
}

// scatter: build edge records {src, dis[src]} grouped by dst
__global__ void scatter_edges(const int* __restrict__ src, const int* __restrict__ dst,
                              const int* __restrict__ offsets, int* __restrict__ cursor,
                              const float* __restrict__ dis,
                              int2* __restrict__ edata, int n) {
    int i = blockIdx.x * blockDim.x + threadIdx.x;
    if (i < n) {
        int d = dst[i];
        int s = src[i];
        int pos = offsets[d] + atomicAdd(&cursor[d], 1);
        edata[pos] = make_int2(s, __float_as_int(dis[s]));
    }
}

__global__ void build_wcat(const float* __restrict__ Wmu, const float* __restrict__ Wlv,
                           float* __restrict__ Wcat) {
    int i = blockIdx.x * blockDim.x + threadIdx.x;  // 128*64
    if (i < DHID * DO2) {
        int k = i >> 6, j = i & 63;
        Wcat[i] = (j < DOUT) ? Wmu[k * DOUT + j] : Wlv[k * DOUT + (j - DOUT)];
    }
}

// ---------- aggregateX: axb[v] = bf16( dis_v * (sum_e dis_s*xb[s] + dis_v*xb[v]) )
// one wave per node; 8 lanes per edge, uint4 (8 feats) per lane, 8 edges in flight
__global__ __launch_bounds__(256) void aggregateX(const uint* __restrict__ xb,   // bf16x2 [N,32]
                                                  const int* __restrict__ offsets,
                                                  const int2* __restrict__ edata,
                                                  const float* __restrict__ dis,
                                                  uint* __restrict__ axb) {
    int wave = threadIdx.x >> 6;
    int lane = threadIdx.x & 63;
    int oct  = lane >> 3;        // edge slot 0..7
    int j4   = (lane & 7) * 4;   // uint index within row
    int v = blockIdx.x * 4 + wave;
    if (v >= NN) return;
    int beg = offsets[v], end = offsets[v + 1];
    float a0 = 0.f, a1 = 0.f, a2 = 0.f, a3 = 0.f, a4 = 0.f, a5 = 0.f, a6 = 0.f, a7 = 0.f;
    for (int base = beg; base < end; base += 8) {
        int e = base + oct;
        int2 r = (e < end) ? edata[e] : make_int2(0, 0);
        uint4 p = *(const uint4*)(xb + (size_t)r.x * 32 + j4);
        float c = __int_as_float(r.y);
        a0 += c * bflo(p.x); a1 += c * bfhi(p.x);
        a2 += c * bflo(p.y); a3 += c * bfhi(p.y);
        a4 += c * bflo(p.z); a5 += c * bfhi(p.z);
        a6 += c * bflo(p.w); a7 += c * bfhi(p.w);
    }
#pragma unroll
    for (int m = 8; m < 64; m <<= 1) {
        a0 += __shfl_xor(a0, m); a1 += __shfl_xor(a1, m);
        a2 += __shfl_xor(a2, m); a3 += __shfl_xor(a3, m);
        a4 += __shfl_xor(a4, m); a5 += __shfl_xor(a5, m);
        a6 += __shfl_xor(a6, m); a7 += __shfl_xor(a7, m);
    }
    float dv = dis[v];
    uint4 pv = *(const uint4*)(xb + (size_t)v * 32 + j4);
    a0 += dv * bflo(pv.x); a1 += dv * bfhi(pv.x);
    a2 += dv * bflo(pv.y); a3 += dv * bfhi(pv.y);
    a4 += dv * bflo(pv.z); a5 += dv * bfhi(pv.z);
    a6 += dv * bflo(pv.w); a7 += dv * bfhi(pv.w);
    if (lane < 8) {
        uint4 o;
        o.x = pack2(dv * a0, dv * a1);
        o.y = pack2(dv * a2, dv * a3);
        o.z = pack2(dv * a4, dv * a5);
        o.w = pack2(dv * a6, dv * a7);
        *(uint4*)(axb + (size_t)v * 32 + j4) = o;
    }
}

__device__ __forceinline__ float selu_f(float v) {
    const float scale = 1.0507009873554805f;
    const float alpha = 1.6732632423543772f;
    return scale * (v > 0.f ? v : alpha * (expf(v) - 1.f));
}

// ---------- GEMM1: axb bf16[N,64] @ W1[64,128] + b1, selu -> h bf16[N,128] ----------
__global__ __launch_bounds__(256) void gemm1(const uint* __restrict__ axb,
                                             const float* __restrict__ W,
                                             const float* __restrict__ b,
                                             ushort* __restrict__ out) {
    __shared__ __align__(16) float xT[DIN][64];     // [k][row]  16 KB
    __shared__ __align__(16) float Ws[DIN][DHID];   // 32 KB
    __shared__ __align__(16) float Bs[DHID];
    int tid = threadIdx.x;
    int row0 = blockIdx.x * 64;

    for (int t = tid; t < (DIN * DHID) / 4; t += 256)
        ((float4*)Ws)[t] = ((const float4*)W)[t];
    if (tid < DHID / 4) ((float4*)Bs)[tid] = ((const float4*)b)[tid];

    int rr = tid & 63;
    int kq = tid >> 6;               // 0..3
    int grow = row0 + rr;
    for (int k0 = kq * 8; k0 < DIN; k0 += 32) {
        uint4 pv = make_uint4(0, 0, 0, 0);
        if (grow < NN) pv = *(const uint4*)(axb + (size_t)grow * 32 + k0 / 2);
        xT[k0 + 0][rr] = bflo(pv.x); xT[k0 + 1][rr] = bfhi(pv.x);
        xT[k0 + 2][rr] = bflo(pv.y); xT[k0 + 3][rr] = bfhi(pv.y);
        xT[k0 + 4][rr] = bflo(pv.z); xT[k0 + 5][rr] = bfhi(pv.z);
        xT[k0 + 6][rr] = bflo(pv.w); xT[k0 + 7][rr] = bfhi(pv.w);
    }
    __syncthreads();

    int tx = tid & 31;               // col group
    int ty = tid >> 5;               // 0..7 row group
    int c0 = tx * 4;
    int r0 = ty * 8;
    float acc[8][4];
#pragma unroll
    for (int i = 0; i < 8; i++)
#pragma unroll
        for (int j = 0; j < 4; j++) acc[i][j] = 0.f;

#pragma unroll 4
    for (int k = 0; k < DIN; k++) {
        float4 a0 = *(const float4*)&xT[k][r0];
        float4 a1 = *(const float4*)&xT[k][r0 + 4];
        float4 w  = *(const float4*)&Ws[k][c0];
        float av[8] = {a0.x, a0.y, a0.z, a0.w, a1.x, a1.y, a1.z, a1.w};
        float wv[4] = {w.x, w.y, w.z, w.w};
#pragma unroll
        for (int i = 0; i < 8; i++)
#pragma unroll
            for (int j = 0; j < 4; j++) acc[i][j] += av[i] * wv[j];
    }

    float4 bb = *(const float4*)&Bs[c0];
    float bv[4] = {bb.x, bb.y, bb.z, bb.w};
#pragma unroll
    for (int i = 0; i < 8; i++) {
        int orow = row0 + r0 + i;
        if (orow < NN) {
            float o0 = selu_f(acc[i][0] + bv[0]);
            float o1 = selu_f(acc[i][1] + bv[1]);
            float o2 = selu_f(acc[i][2] + bv[2]);
            float o3 = selu_f(acc[i][3] + bv[3]);
            *(uint2*)(out + (size_t)orow * DHID + c0) = make_uint2(pack2(o0, o1), pack2(o2, o3));
        }
    }
}

// ---------- GEMM2: h bf16[N,128] @ Wcat[128,64] -> hw2 bf16[N,64] ----------
__global__ __launch_bounds__(256) void gemm2(const ushort* __restrict__ h,
                                             const float* __restrict__ W,
                                             ushort* __restrict__ out) {
    __shared__ __align__(16) float hsT[DHID][64];   // [k][row] 32 KB
    __shared__ __align__(16) float Ws[DHID][DO2];   // 32 KB
    int tid = threadIdx.x;
    int row0 = blockIdx.x * 64;

    for (int t = tid; t < (DHID * DO2) / 4; t += 256)
        ((float4*)Ws)[t] = ((const float4*)W)[t];

    int rr = tid & 63;
    int kq = tid >> 6;               // 0..3
    int grow = row0 + rr;
    for (int k0 = kq * 8; k0 < DHID; k0 += 32) {
        uint4 pv = make_uint4(0, 0, 0, 0);
        if (grow < NN) pv = *(const uint4*)(h + (size_t)grow * DHID + k0);
        hsT[k0 + 0][rr] = bflo(pv.x); hsT[k0 + 1][rr] = bfhi(pv.x);
        hsT[k0 + 2][rr] = bflo(pv.y); hsT[k0 + 3][rr] = bfhi(pv.y);
        hsT[k0 + 4][rr] = bflo(pv.z); hsT[k0 + 5][rr] = bfhi(pv.z);
        hsT[k0 + 6][rr] = bflo(pv.w); hsT[k0 + 7][rr] = bfhi(pv.w);
    }
    __syncthreads();

    int tx = tid & 15;
    int ty = tid >> 4;               // 0..15
    int c0 = tx * 4;
    int r0 = ty * 4;
    float acc[4][4];
#pragma unroll
    for (int i = 0; i < 4; i++)
#pragma unroll
        for (int j = 0; j < 4; j++) acc[i][j] = 0.f;

#pragma unroll 4
    for (int k = 0; k < DHID; k++) {
        float4 a = *(const float4*)&hsT[k][r0];
        float4 w = *(const float4*)&Ws[k][c0];
        float av[4] = {a.x, a.y, a.z, a.w};
        float wv[4] = {w.x, w.y, w.z, w.w};
#pragma unroll
        for (int i = 0; i < 4; i++)
#pragma unroll
            for (int j = 0; j < 4; j++) acc[i][j] += av[i] * wv[j];
    }

#pragma unroll
    for (int i = 0; i < 4; i++) {
        int orow = row0 + r0 + i;
        if (orow < NN) {
            uint p0 = pack2(acc[i][0], acc[i][1]);
            uint p1 = pack2(acc[i][2], acc[i][3]);
            *(uint2*)(out + (size_t)orow * DO2 + c0) = make_uint2(p0, p1);
        }
    }
}

// ---------- aggregate2: same octet structure; epilogue adds bias, splits mu/lv ----------
__global__ __launch_bounds__(256) void aggregate2(const uint* __restrict__ hw2b,  // bf16x2 [N,32]
                                                  const int* __restrict__ offsets,
                                                  const int2* __restrict__ edata,
                                                  const float* __restrict__ dis,
                                                  const float* __restrict__ bmu,
                                                  const float* __restrict__ blv,
                                                  float* __restrict__ out) {
    int wave = threadIdx.x >> 6;
    int lane = threadIdx.x & 63;
    int oct  = lane >> 3;
    int j4   = (lane & 7) * 4;
    int v = blockIdx.x * 4 + wave;
    if (v >= NN) return;
    int beg = offsets[v], end = offsets[v + 1];
    float a0 = 0.f, a1 = 0.f, a2 = 0.f, a3 = 0.f, a4 = 0.f, a5 = 0.f, a6 = 0.f, a7 = 0.f;
    for (int base = beg; base < end; base += 8) {
        int e = base + oct;
        int2 r = (e < end) ? edata[e] : make_int2(0, 0);
        uint4 p = *(const uint4*)(hw2b + (size_t)r.x * 32 + j4);
        float c = __int_as_float(r.y);
        a0 += c * bflo(p.x); a1 += c * bfhi(p.x);
        a2 += c * bflo(p.y); a3 += c * bfhi(p.y);
        a4 += c * bflo(p.z); a5 += c * bfhi(p.z);
        a6 += c * bflo(p.w); a7 += c * bfhi(p.w);
    }
#pragma unroll
    for (int m = 8; m < 64; m <<= 1) {
        a0 += __shfl_xor(a0, m); a1 += __shfl_xor(a1, m);
        a2 += __shfl_xor(a2, m); a3 += __shfl_xor(a3, m);
        a4 += __shfl_xor(a4, m); a5 += __shfl_xor(a5, m);
        a6 += __shfl_xor(a6, m); a7 += __shfl_xor(a7, m);
    }
    float dv = dis[v];
    uint4 pv = *(const uint4*)(hw2b + (size_t)v * 32 + j4);
    a0 += dv * bflo(pv.x); a1 += dv * bfhi(pv.x);
    a2 += dv * bflo(pv.y); a3 += dv * bfhi(pv.y);
    a4 += dv * bflo(pv.z); a5 += dv * bfhi(pv.z);
    a6 += dv * bflo(pv.w); a7 += dv * bfhi(pv.w);
    if (lane < 8) {
        int j = lane;                          // 0..7: feats 8j..8j+7
        const float* bp = (j < 4) ? (bmu + 8 * j) : (blv + 8 * j - 32);
        float* op = (j < 4) ? (out + (size_t)v * DOUT + 8 * j)
                            : (out + (size_t)NN * DOUT + (size_t)v * DOUT + 8 * j - 32);
        float4 b0 = *(const float4*)bp;
        float4 b1 = *(const float4*)(bp + 4);
        *(float4*)op       = make_float4(dv * a0 + b0.x, dv * a1 + b0.y,
                                         dv * a2 + b0.z, dv * a3 + b0.w);
        *(float4*)(op + 4) = make_float4(dv * a4 + b1.x, dv * a5 + b1.y,
                                         dv * a6 + b1.z, dv * a7 + b1.w);
    }
}

extern "C" void kernel_launch(void* const* d_in, const int* in_sizes, int n_in,
                              void* d_out, int out_size, void* d_ws, size_t ws_size,
                              hipStream_t stream) {
    const float* x   = (const float*)d_in[0];
    const int*   ei  = (const int*)d_in[1];
    const int*   e_src = ei;            // edge_index[0]
    const int*   e_dst = ei + NE;       // edge_index[1]
    const float* W1  = (const float*)d_in[2];
    const float* b1  = (const float*)d_in[3];
    const float* Wmu = (const float*)d_in[4];
    const float* bmu = (const float*)d_in[5];
    const float* Wlv = (const float*)d_in[6];
    const float* blv = (const float*)d_in[7];
    float* out = (float*)d_out;

    char* ws = (char*)d_ws;
    size_t off = 0;
    auto alloc = [&](size_t bytes) -> void* {
        void* p = ws + off;
        off += (bytes + 255) & ~(size_t)255;
        return p;
    };
    int*    counts    = (int*)alloc((size_t)NN * 4);
    int*    cursor    = (int*)alloc((size_t)NN * 4);
    int*    offsets   = (int*)alloc((size_t)(NN + 1) * 4);
    int2*   edata     = (int2*)alloc((size_t)NE * 8);
    int*    blocksums = (int*)alloc((size_t)SCAN_NB * 4);
    float*  dis       = (float*)alloc((size_t)NN * 4);
    float*  Wcat      = (float*)alloc((size_t)DHID * DO2 * 4);
    uint*   xb        = (uint*)alloc((size_t)NN * DIN * 2);     // bf16 x, 12.8 MB
    uint*   axb       = (uint*)alloc((size_t)NN * DIN * 2);     // bf16 A·x, 12.8 MB
    ushort* h         = (ushort*)alloc((size_t)NN * DHID * 2);  // bf16 h, 25.6 MB
    uint*   hw2b      = xb;   // xb dead after aggregateX; 12.8 MB fits

    zero_two<<<(NN + 255) / 256, 256, 0, stream>>>(counts, cursor, NN);
    count_dst<<<(NE + 255) / 256, 256, 0, stream>>>(e_dst, counts, NE);
    compute_dis<<<(NN + 255) / 256, 256, 0, stream>>>(counts, dis, NN);
    scan_phase1<<<SCAN_NB, 1024, 0, stream>>>(counts, offsets, blocksums, NN);
    scan_phase2<<<1, 128, 0, stream>>>(blocksums, SCAN_NB);
    scan_phase3<<<SCAN_NB, 1024, 0, stream>>>(offsets, blocksums, NN);
    scatter_edges<<<(NE + 255) / 256, 256, 0, stream>>>(e_src, e_dst, offsets, cursor, dis, edata, NE);
    build_wcat<<<(DHID * DO2 + 255) / 256, 256, 0, stream>>>(Wmu, Wlv, Wcat);
    cast_x<<<((NN * DIN / 2) + 255) / 256, 256, 0, stream>>>(x, xb, NN * DIN / 2);

    int gblocks = (NN + 63) / 64;
    aggregateX<<<(NN + 3) / 4, 256, 0, stream>>>(xb, offsets, edata, dis, axb);
    gemm1<<<gblocks, 256, 0, stream>>>(axb, W1, b1, h);
    gemm2<<<gblocks, 256, 0, stream>>>(h, Wcat, (ushort*)hw2b);
    aggregate2<<<(NN + 3) / 4, 256, 0, stream>>>(hw2b, offsets, edata, dis, bmu, blv, out);
}